// Round 5
// baseline (1272.336 us; speedup 1.0000x reference)
//
#include <hip/hip_runtime.h>
#include <stdint.h>

typedef unsigned int u32;
typedef unsigned short u16;
typedef __attribute__((ext_vector_type(8))) short short8;
typedef __attribute__((ext_vector_type(4))) float f32x4;

#define N_SRC0 500000
#define N_DST0 100000
#define N_DST1 10000
#define N_DST2 1024
#define NCLS 47

#define NB0 98
#define NB1 10
#define NBLK 109

#define EQCAP 384   // per-wave staged edge queue entries

// ---------- bf16 helpers ----------
static __device__ __forceinline__ float bf16_lo(u32 v) { return __uint_as_float(v << 16); }
static __device__ __forceinline__ float bf16_hi(u32 v) { return __uint_as_float(v & 0xffff0000u); }
static __device__ __forceinline__ float bf16_to_f(u16 s) { return __uint_as_float(((u32)s) << 16); }
static __device__ __forceinline__ u16 f_to_bf16(float f) {
    u32 u = __float_as_uint(f);
    u32 r = u + 0x7fffu + ((u >> 16) & 1u);   // round-to-nearest-even
    return (u16)(r >> 16);
}

// ---------- workspace layout (bytes, 16-aligned) ----------
#define OFF_X1     0u            // 51,200,000
#define OFF_X2     51200000u     // 5,120,000
#define OFF_CSR0   56320000u     // 4,000,000
#define OFF_CSR1   60320000u     // 400,000
#define OFF_CSR2   60720000u     // 40,960
#define OFF_RS0    60760960u     // 400,016
#define OFF_CUR0   61160976u     // 400,000
#define OFF_RS1    61560976u     // 40,016
#define OFF_CUR1   61600992u     // 40,000
#define OFF_RS2    61640992u     // 4,112
#define OFF_CUR2   61645104u     // 4,096
#define OFF_CNT0   61649200u     // 400,000  } zero span
#define OFF_DS1    62049200u     // 400,000
#define OFF_DD1    62449200u     // 40,000
#define OFF_DS2    62489200u     // 40,000
#define OFF_DD2    62529200u     // 4,096    } zero span end
#define ZERO_OFF   OFF_CNT0
#define ZERO_N4    55256u
#define OFF_WF0    62533296u     // 65,536 (bf16 B-frags W0)
#define OFF_WF1    62598832u     // 65,536
#define OFF_WC2    62664368u     // 24,064
#define OFF_BC0    62688432u     // 512
#define OFF_BC1    62688944u     // 512
#define OFF_BC2    62689456u     // 256
#define OFF_FLAG   62689712u     // 64
#define OFF_BSUM   62689776u     // 448
#define OFF_BOFF   62690224u     // 448

// ---------- mega-prep ----------
__global__ __launch_bounds__(256) void k_prep(
    const u32* __restrict__ feats_w,
    const void* __restrict__ W0, const void* __restrict__ b0,
    const void* __restrict__ W1, const void* __restrict__ b1,
    const void* __restrict__ W2, const void* __restrict__ b2,
    float4* __restrict__ zbase,
    u16* __restrict__ wf0, u16* __restrict__ wf1,
    float* __restrict__ wc2, float* __restrict__ bc0,
    float* __restrict__ bc1, float* __restrict__ bc2,
    u32* __restrict__ flag)
{
    int b = blockIdx.x, t = threadIdx.x;
    if (b < 216) {
        u32 i = b * 256 + t;
        if (i < ZERO_N4) zbase[i] = make_float4(0.f, 0.f, 0.f, 0.f);
        return;
    }
    if (b == 216) {
        if (t < 64) {
            u32 u = feats_w[t];
            int e = (u >> 23) & 0xff;
            unsigned long long m = __ballot(e >= 0xC0);
            if (t == 0) *flag = (m != 0ull) ? 1u : 0u;
        }
        return;
    }
    __shared__ u32 lflag;
    if (b < 233) {                       // W0/W1 -> bf16 B-fragments
        const void* W = (b < 225) ? W0 : W1;
        u16* dst = (b < 225) ? wf0 : wf1;
        int base = ((b < 225) ? (b - 217) : (b - 225)) * 256;
        if (t == 0) lflag = 0u;
        __syncthreads();
        if (t < 64) { u32 u = ((const u32*)W)[t]; if (((u >> 23) & 0xff) >= 0xC0) atomicOr(&lflag, 1u); }
        __syncthreads();
        bool bf = (lflag != 0u);
        int idx = base + t;
        int fid = idx >> 6, lane = idx & 63;
        int nt = fid >> 2, ks = fid & 3;
        #pragma unroll
        for (int j = 0; j < 8; ++j) {
            int k = ks * 32 + (lane >> 4) * 8 + j;
            int n = nt * 16 + (lane & 15);
            u16 v = bf ? ((const u16*)W)[k * 128 + n]
                       : f_to_bf16(((const float*)W)[k * 128 + n]);
            dst[idx * 8 + j] = v;
        }
        return;
    }
    if (b < 257) {                       // W2 -> fp32
        if (t == 0) lflag = 0u;
        __syncthreads();
        if (t < 64) { u32 u = ((const u32*)W2)[t]; if (((u >> 23) & 0xff) >= 0xC0) atomicOr(&lflag, 1u); }
        __syncthreads();
        bool bf = (lflag != 0u);
        int i = (b - 233) * 256 + t;
        if (i < 128 * NCLS)
            wc2[i] = bf ? bf16_to_f(((const u16*)W2)[i]) : ((const float*)W2)[i];
        return;
    }
    if (t < 128) { bc0[t] = ((const float*)b0)[t]; bc1[t] = ((const float*)b1)[t]; }
    if (t < NCLS) bc2[t] = ((const float*)b2)[t];
}

// ---------- degree histograms ----------
__global__ __launch_bounds__(256) void k_deg_all(
    const int* __restrict__ dst0,
    const int* __restrict__ src1, const int* __restrict__ dst1,
    const int* __restrict__ src2, const int* __restrict__ dst2,
    u32* __restrict__ cnt0, u32* __restrict__ dS1, u32* __restrict__ dD1,
    u32* __restrict__ dS2, u32* __restrict__ dD2, int E0, int E1, int E2)
{
    int i = blockIdx.x * 256 + threadIdx.x;
    if (i < E0) atomicAdd(&cnt0[dst0[i]], 1u);
    if (i < E1) { atomicAdd(&dS1[src1[i]], 1u); atomicAdd(&dD1[dst1[i]], 1u); }
    if (i < E2) { atomicAdd(&dS2[src2[i]], 1u); atomicAdd(&dD2[dst2[i]], 1u); }
}

// ---------- hierarchical scan ----------
static __device__ __forceinline__ void seg_map(int b, const u32* cnt0, const u32* dD1,
                                               const u32* dD2, const u32*& cnt,
                                               int& base, int& n, int& seg) {
    if (b < NB0)            { cnt = cnt0; base = b * 1024;          n = N_DST0; seg = 0; }
    else if (b < NB0 + NB1) { cnt = dD1;  base = (b - NB0) * 1024;  n = N_DST1; seg = 1; }
    else                    { cnt = dD2;  base = 0;                 n = N_DST2; seg = 2; }
}

__global__ __launch_bounds__(256) void k_bsum(
    const u32* __restrict__ cnt0, const u32* __restrict__ dD1,
    const u32* __restrict__ dD2, u32* __restrict__ bsum)
{
    const u32* cnt; int base, n, seg;
    seg_map(blockIdx.x, cnt0, dD1, dD2, cnt, base, n, seg);
    int t = threadIdx.x;
    int i0 = base + t * 4;
    u32 s = 0;
    #pragma unroll
    for (int j = 0; j < 4; ++j) { int i = i0 + j; if (i < n) s += cnt[i]; }
    #pragma unroll
    for (int off = 32; off; off >>= 1) s += __shfl_down(s, off, 64);
    __shared__ u32 wsum[4];
    if ((t & 63) == 0) wsum[t >> 6] = s;
    __syncthreads();
    if (t == 0) bsum[blockIdx.x] = wsum[0] + wsum[1] + wsum[2] + wsum[3];
}

__global__ void k_bscan(const u32* __restrict__ bsum, u32* __restrict__ boff,
                        u32* __restrict__ rs0, u32* __restrict__ rs1,
                        u32* __restrict__ rs2)
{
    if (threadIdx.x != 0) return;
    u32 run = 0;
    for (int b = 0; b < NB0; ++b) { boff[b] = run; run += bsum[b]; }
    rs0[N_DST0] = run;
    run = 0;
    for (int b = NB0; b < NB0 + NB1; ++b) { boff[b] = run; run += bsum[b]; }
    rs1[N_DST1] = run;
    boff[NB0 + NB1] = 0;
    rs2[N_DST2] = bsum[NB0 + NB1];
}

__global__ __launch_bounds__(256) void k_bwrite(
    const u32* __restrict__ cnt0, const u32* __restrict__ dD1,
    const u32* __restrict__ dD2, const u32* __restrict__ boff,
    u32* __restrict__ rs0, u32* __restrict__ cur0,
    u32* __restrict__ rs1, u32* __restrict__ cur1,
    u32* __restrict__ rs2, u32* __restrict__ cur2)
{
    const u32* cnt; int base, n, seg;
    seg_map(blockIdx.x, cnt0, dD1, dD2, cnt, base, n, seg);
    u32 *rs, *cur;
    if (seg == 0)      { rs = rs0; cur = cur0; }
    else if (seg == 1) { rs = rs1; cur = cur1; }
    else               { rs = rs2; cur = cur2; }

    int t = threadIdx.x;
    int i0 = base + t * 4;
    u32 c[4]; u32 s = 0;
    #pragma unroll
    for (int j = 0; j < 4; ++j) {
        int i = i0 + j;
        c[j] = (i < n) ? cnt[i] : 0u;
        s += c[j];
    }
    __shared__ u32 sc[256];
    sc[t] = s;
    __syncthreads();
    #pragma unroll
    for (int off = 1; off < 256; off <<= 1) {
        u32 v = (t >= off) ? sc[t - off] : 0u;
        __syncthreads();
        sc[t] += v;
        __syncthreads();
    }
    u32 ex = sc[t] - s + boff[blockIdx.x];
    #pragma unroll
    for (int j = 0; j < 4; ++j) {
        int i = i0 + j;
        if (i < n) { rs[i] = ex; cur[i] = ex; ex += c[j]; }
    }
}

// ---------- CSR fill ----------
__global__ __launch_bounds__(256) void k_fill(
    const int* __restrict__ src0, const int* __restrict__ dst0,
    const int* __restrict__ src1, const int* __restrict__ dst1,
    const int* __restrict__ src2, const int* __restrict__ dst2,
    u32* __restrict__ cur0, int* __restrict__ csr0,
    u32* __restrict__ cur1, int* __restrict__ csr1,
    u32* __restrict__ cur2, int* __restrict__ csr2,
    int E0, int E1, int E2)
{
    int i = blockIdx.x * 256 + threadIdx.x;
    if (i < E0) { u32 p = atomicAdd(&cur0[dst0[i]], 1u); csr0[p] = src0[i]; }
    if (i < E1) { u32 p = atomicAdd(&cur1[dst1[i]], 1u); csr1[p] = src1[i]; }
    if (i < E2) { u32 p = atomicAdd(&cur2[dst2[i]], 1u); csr2[p] = src2[i]; }
}

// ---------- fused layer: edge-parallel CSR agg (LDS fp32) -> bf16 -> MFMA ----------
// out[I] = relu( (sum_e Ain[src_e]) @ W * pre(I) + b ) * post(I)
// Wave wv owns local rows wv*12..+11. Edge queue staged in LDS; hot loop keeps
// 8 gathers (4KB) in flight, accumulates via ds_add_f32 (2-way banks = free).
__global__ __launch_bounds__(256) void k_layer(
    const void* __restrict__ Ain, const u32* __restrict__ flag,
    const u32* __restrict__ rs, const int* __restrict__ csr,
    const int* __restrict__ inv, const int* __restrict__ shuf,
    const u32* __restrict__ preDeg, const u32* __restrict__ postDeg,
    const u16* __restrict__ Wfrag, const float* __restrict__ bias,
    float* __restrict__ out, int rows)
{
    __shared__ __align__(16) float Af[48][136];   // fp32 accum; bf16 overlaid after
    __shared__ u32  eqS[4 * EQCAP];
    __shared__ u32  rowBegS[48], rowCntS[48], stgS[48];
    __shared__ float preS[48], postS[48], bS[128];

    int tid = threadIdx.x;
    int wv = tid >> 6, lane = tid & 63;
    int I0 = blockIdx.x * 48;
    int r0 = wv * 12;

    if (tid < 48) {
        int I = I0 + tid;
        u32 beg = 0, cnt = 0; float pre = 1.f, post = 1.f;
        if (I < rows) {
            int ar = shuf ? inv[shuf[I]] : I;
            beg = rs[ar]; cnt = rs[ar + 1] - beg;
            if (preDeg)  { u32 d = preDeg[I];  pre  = rsqrtf((float)(d > 1u ? d : 1u)); }
            if (postDeg) { u32 d = postDeg[I]; post = rsqrtf((float)(d > 1u ? d : 1u)); }
        }
        rowBegS[tid] = beg; rowCntS[tid] = cnt;
        preS[tid] = pre; postS[tid] = post;
    }
    if (tid < 128) bS[tid] = bias[tid];
    for (int i = tid; i < 48 * 136; i += 256) ((float*)Af)[i] = 0.f;

    // B-fragments (wave wv owns n-tiles 2wv, 2wv+1) — issue before barrier
    short8 bfr[2][4];
    #pragma unroll
    for (int nt = 0; nt < 2; ++nt)
        #pragma unroll
        for (int ks = 0; ks < 4; ++ks) {
            int fid = (wv * 2 + nt) * 4 + ks;
            bfr[nt][ks] = *(const short8*)(Wfrag + (size_t)(fid * 64 + lane) * 8);
        }
    __syncthreads();

    // ---- stage edge queue: (localrow<<26)|src, one vector load per row ----
    u32* eqw = eqS + wv * EQCAP;
    int off = 0;
    for (int i = 0; i < 12; ++i) {
        int r = r0 + i;
        int cnt = (int)rowCntS[r];
        int take = cnt > 64 ? 64 : cnt;
        if (off + take > EQCAP) take = (EQCAP > off) ? (EQCAP - off) : 0;
        if (lane == 0) stgS[r] = (u32)take;
        if (lane < take) {
            int s = csr[rowBegS[r] + lane];
            eqw[off + lane] = ((u32)i << 26) | (u32)s;
        }
        off += take;
    }
    int W = off;

    // ---- hot loop: 8 edges in flight per wait ----
    bool bfp = flag && (*flag != 0u);
    for (int base = 0; base < W; base += 8) {
        u32 pk[8];
        #pragma unroll
        for (int j = 0; j < 8; ++j) {
            int ii = base + j; if (ii >= W) ii = W - 1;
            pk[j] = eqw[ii];
        }
        float xx[8], yy[8];
        if (bfp) {
            const u32* f = (const u32*)Ain;
            #pragma unroll
            for (int j = 0; j < 8; ++j) {
                u32 v = f[(size_t)(pk[j] & 0x03ffffffu) * 64 + lane];
                xx[j] = bf16_lo(v); yy[j] = bf16_hi(v);
            }
        } else {
            const float2* f = (const float2*)Ain;
            #pragma unroll
            for (int j = 0; j < 8; ++j) {
                float2 v = f[(size_t)(pk[j] & 0x03ffffffu) * 64 + lane];
                xx[j] = v.x; yy[j] = v.y;
            }
        }
        #pragma unroll
        for (int j = 0; j < 8; ++j) {
            if (base + j < W) {
                int r = r0 + (int)(pk[j] >> 26);
                atomicAdd(&Af[r][2 * lane],     xx[j]);
                atomicAdd(&Af[r][2 * lane + 1], yy[j]);
            }
        }
    }

    // ---- fallback for rows with degree > staged (never for Poisson(10)) ----
    for (int i = 0; i < 12; ++i) {
        int r = r0 + i;
        int cnt = (int)rowCntS[r], st = (int)stgS[r];
        u32 beg = rowBegS[r];
        for (int e = st; e < cnt; ++e) {
            int s = csr[beg + e];
            float x, y;
            if (bfp) { u32 v = ((const u32*)Ain)[(size_t)s * 64 + lane]; x = bf16_lo(v); y = bf16_hi(v); }
            else     { float2 v = ((const float2*)Ain)[(size_t)s * 64 + lane]; x = v.x; y = v.y; }
            atomicAdd(&Af[r][2 * lane],     x);
            atomicAdd(&Af[r][2 * lane + 1], y);
        }
    }

    // ---- in-place fp32 -> bf16 (wave-owned rows; read precedes write in-wave) ----
    u16* Ab = (u16*)Af;                  // row r at u16 index r*272
    for (int i = 0; i < 12; ++i) {
        int r = r0 + i;
        float x = Af[r][2 * lane], y = Af[r][2 * lane + 1];
        u32 pkd = ((u32)f_to_bf16(y) << 16) | (u32)f_to_bf16(x);
        ((u32*)(Ab + (size_t)r * 272))[lane] = pkd;
    }
    __syncthreads();

    // ---- MFMA: 3 m-tiles x 2 n-tiles, K=128 in 4 steps ----
    f32x4 acc[2][3];
    #pragma unroll
    for (int nt = 0; nt < 2; ++nt)
        #pragma unroll
        for (int mt = 0; mt < 3; ++mt) acc[nt][mt] = (f32x4){0.f, 0.f, 0.f, 0.f};

    #pragma unroll
    for (int ks = 0; ks < 4; ++ks) {
        short8 af[3];
        #pragma unroll
        for (int mt = 0; mt < 3; ++mt) {
            int row = mt * 16 + (lane & 15);
            int k0 = ks * 32 + (lane >> 4) * 8;
            af[mt] = *(const short8*)(Ab + (size_t)row * 272 + k0);
        }
        #pragma unroll
        for (int nt = 0; nt < 2; ++nt)
            #pragma unroll
            for (int mt = 0; mt < 3; ++mt)
                acc[nt][mt] = __builtin_amdgcn_mfma_f32_16x16x32_bf16(
                    af[mt], bfr[nt][ks], acc[nt][mt], 0, 0, 0);
    }

    // ---- epilogue ----
    int quad = lane >> 4, cl = lane & 15;
    #pragma unroll
    for (int nt = 0; nt < 2; ++nt) {
        int col = (wv * 2 + nt) * 16 + cl;
        float bb = bS[col];
        #pragma unroll
        for (int mt = 0; mt < 3; ++mt) {
            #pragma unroll
            for (int rg = 0; rg < 4; ++rg) {
                int lr = mt * 16 + quad * 4 + rg;
                int I = I0 + lr;
                if (I < rows) {
                    float v = acc[nt][mt][rg] * preS[lr] + bb;
                    v = v > 0.f ? v : 0.f;
                    out[(size_t)I * 128 + col] = v * postS[lr];
                }
            }
        }
    }
}

// ---------- fused final layer ----------
__global__ __launch_bounds__(256) void k_layer2(
    const float2* __restrict__ x2, const u32* __restrict__ rs,
    const int* __restrict__ csr, const u32* __restrict__ preDeg,
    const float* __restrict__ Wc2, const float* __restrict__ bc2,
    void* __restrict__ out, const u32* __restrict__ flag)
{
    __shared__ float t2[16][128];
    int tid = threadIdx.x;
    int wv = tid >> 6, lane = tid & 63;
    int R0 = blockIdx.x * 16;

    for (int i = 0; i < 4; ++i) {
        int r = wv * 4 + i;
        int R = R0 + r;
        float x = 0.f, y = 0.f;
        u32 e = rs[R], end = rs[R + 1];
        for (; e + 4 <= end; e += 4) {
            int s0 = csr[e], s1 = csr[e+1], s2 = csr[e+2], s3 = csr[e+3];
            float2 v0 = x2[(size_t)s0 * 64 + lane];
            float2 v1 = x2[(size_t)s1 * 64 + lane];
            float2 v2 = x2[(size_t)s2 * 64 + lane];
            float2 v3 = x2[(size_t)s3 * 64 + lane];
            x += v0.x + v1.x + v2.x + v3.x;
            y += v0.y + v1.y + v2.y + v3.y;
        }
        for (; e < end; ++e) {
            float2 v = x2[(size_t)csr[e] * 64 + lane];
            x += v.x; y += v.y;
        }
        t2[r][2 * lane] = x;
        t2[r][2 * lane + 1] = y;
    }
    __syncthreads();

    bool bfp = flag && (*flag != 0u);
    for (int idx = tid; idx < 16 * NCLS; idx += 256) {
        int r = idx / NCLS, c = idx - NCLS * r;
        float a = 0.f;
        #pragma unroll 8
        for (int k = 0; k < 128; ++k) a = fmaf(t2[r][k], Wc2[k * NCLS + c], a);
        u32 d = preDeg[R0 + r];
        float v = a * rsqrtf((float)(d > 1u ? d : 1u)) + bc2[c];
        int g = (R0 + r) * NCLS + c;
        if (bfp) ((u16*)out)[g] = f_to_bf16(v);
        else     ((float*)out)[g] = v;
    }
}

extern "C" void kernel_launch(void* const* d_in, const int* in_sizes, int n_in,
                              void* d_out, int out_size, void* d_ws, size_t ws_size,
                              hipStream_t stream)
{
    (void)n_in; (void)out_size; (void)ws_size;
    const void* feats = d_in[0];
    const int* src0 = (const int*)d_in[1];
    const int* dst0 = (const int*)d_in[2];
    const int* src1 = (const int*)d_in[3];
    const int* dst1 = (const int*)d_in[4];
    const int* src2 = (const int*)d_in[5];
    const int* dst2 = (const int*)d_in[6];
    const int* inv  = (const int*)d_in[7];
    const int* shuf = (const int*)d_in[8];
    const void* W0 = d_in[9];  const void* b0 = d_in[10];
    const void* W1 = d_in[11]; const void* b1 = d_in[12];
    const void* W2 = d_in[13]; const void* b2 = d_in[14];
    int E0 = in_sizes[1], E1 = in_sizes[3], E2 = in_sizes[5];

    char* ws = (char*)d_ws;
    float* x1  = (float*)(ws + OFF_X1);
    float* x2  = (float*)(ws + OFF_X2);
    int* csr0 = (int*)(ws + OFF_CSR0);
    int* csr1 = (int*)(ws + OFF_CSR1);
    int* csr2 = (int*)(ws + OFF_CSR2);
    u32* rs0  = (u32*)(ws + OFF_RS0);
    u32* cur0 = (u32*)(ws + OFF_CUR0);
    u32* rs1  = (u32*)(ws + OFF_RS1);
    u32* cur1 = (u32*)(ws + OFF_CUR1);
    u32* rs2  = (u32*)(ws + OFF_RS2);
    u32* cur2 = (u32*)(ws + OFF_CUR2);
    u32* cnt0 = (u32*)(ws + OFF_CNT0);
    u32* dS1  = (u32*)(ws + OFF_DS1);
    u32* dD1  = (u32*)(ws + OFF_DD1);
    u32* dS2  = (u32*)(ws + OFF_DS2);
    u32* dD2  = (u32*)(ws + OFF_DD2);
    u16* wf0  = (u16*)(ws + OFF_WF0);
    u16* wf1  = (u16*)(ws + OFF_WF1);
    float* wc2 = (float*)(ws + OFF_WC2);
    float* bc0 = (float*)(ws + OFF_BC0);
    float* bc1 = (float*)(ws + OFF_BC1);
    float* bc2 = (float*)(ws + OFF_BC2);
    u32* flag  = (u32*)(ws + OFF_FLAG);
    u32* bsum  = (u32*)(ws + OFF_BSUM);
    u32* boff  = (u32*)(ws + OFF_BOFF);

    k_prep<<<258, 256, 0, stream>>>((const u32*)feats, W0, b0, W1, b1, W2, b2,
                                    (float4*)(ws + ZERO_OFF), wf0, wf1, wc2,
                                    bc0, bc1, bc2, flag);
    k_deg_all<<<(E0 + 255) / 256, 256, 0, stream>>>(dst0, src1, dst1, src2, dst2,
                                                    cnt0, dS1, dD1, dS2, dD2, E0, E1, E2);
    k_bsum<<<NBLK, 256, 0, stream>>>(cnt0, dD1, dD2, bsum);
    k_bscan<<<1, 64, 0, stream>>>(bsum, boff, rs0, rs1, rs2);
    k_bwrite<<<NBLK, 256, 0, stream>>>(cnt0, dD1, dD2, boff,
                                       rs0, cur0, rs1, cur1, rs2, cur2);
    k_fill<<<(E0 + 255) / 256, 256, 0, stream>>>(src0, dst0, src1, dst1, src2, dst2,
                                                 cur0, csr0, cur1, csr1, cur2, csr2,
                                                 E0, E1, E2);
    k_layer<<<(N_DST0 + 47) / 48, 256, 0, stream>>>(
        feats, flag, rs0, csr0, inv, shuf, nullptr, dS1, wf0, bc0, x1, N_DST0);
    k_layer<<<(N_DST1 + 47) / 48, 256, 0, stream>>>(
        x1, nullptr, rs1, csr1, nullptr, nullptr, dD1, dS2, wf1, bc1, x2, N_DST1);
    k_layer2<<<N_DST2 / 16, 256, 0, stream>>>(
        (const float2*)x2, rs2, csr2, dD2, wc2, bc2, d_out, flag);
}